// Round 7
// baseline (233.698 us; speedup 1.0000x reference)
//
#include <hip/hip_runtime.h>
#include <hip/hip_bf16.h>
#include <stdint.h>

typedef __bf16 bf16x8 __attribute__((ext_vector_type(8)));
typedef float  f32x4  __attribute__((ext_vector_type(4)));
typedef float  f32x2  __attribute__((ext_vector_type(2)));

#define N_NODES 100000
#define DIM     128
#define B_BATCH 20000
#define K_NB    32
#define O_OUT   128

// ---------------- K0: transpose + bf16 convert weights ----------------
__global__ void transpose_weights(const float* __restrict__ W1,
                                  const float* __restrict__ Wn,
                                  __bf16* __restrict__ W1t,
                                  __bf16* __restrict__ Wnt) {
    int tid = blockIdx.x * blockDim.x + threadIdx.x;
    if (tid < DIM * DIM) {
        int k = tid >> 7, c = tid & 127;
        W1t[c * DIM + k] = (__bf16)W1[tid];
    }
    int t2 = tid - DIM * DIM;
    if (t2 >= 0 && t2 < 2 * DIM * O_OUT) {
        int k = t2 >> 7, o = t2 & 127;
        Wnt[o * (2 * DIM) + k] = (__bf16)Wn[t2];
    }
}

// ---------------- K1: H = relu(features @ W1 + b1), bf16 out ----------------
// All 32 W1 fragments (128 VGPR) + all 8 A vectors loaded up front -> one
// latency exposure per wave (R4 showed VGPR=40 -> serialized L2 round-trips).
__global__ __launch_bounds__(256, 2)
void gemm_h(const float* __restrict__ X, const __bf16* __restrict__ W1t,
            const float* __restrict__ b1, __bf16* __restrict__ H) {
    const int lane = threadIdx.x & 63;
    const int wave = threadIdx.x >> 6;
    const int rowbase = blockIdx.x * 64 + wave * 16;
    const int r0 = lane & 15;
    const int kg = lane >> 4;          // 0..3
    const int arow = rowbase + r0;
    const int arow_c = arow < N_NODES ? arow : N_NODES - 1;

    // batch-issue all W fragments: wf[kt][ct], 32 x 16B
    bf16x8 wf[4][8];
#pragma unroll
    for (int kt = 0; kt < 4; ++kt)
#pragma unroll
        for (int ct = 0; ct < 8; ++ct)
            wf[kt][ct] = *(const bf16x8*)(W1t + (ct * 16 + r0) * DIM + kt * 32 + kg * 8);

    // batch-issue all A vectors: 8 x f32x4
    f32x4 a[4][2];
#pragma unroll
    for (int kt = 0; kt < 4; ++kt) {
        const float* ap = X + (long)arow_c * DIM + kt * 32 + kg * 8;
        a[kt][0] = *(const f32x4*)ap;
        a[kt][1] = *(const f32x4*)(ap + 4);
    }

    f32x4 acc[8];
#pragma unroll
    for (int t = 0; t < 8; ++t) acc[t] = (f32x4)0.0f;

#pragma unroll
    for (int kt = 0; kt < 4; ++kt) {
        bf16x8 af;
        af[0]=(__bf16)a[kt][0][0]; af[1]=(__bf16)a[kt][0][1];
        af[2]=(__bf16)a[kt][0][2]; af[3]=(__bf16)a[kt][0][3];
        af[4]=(__bf16)a[kt][1][0]; af[5]=(__bf16)a[kt][1][1];
        af[6]=(__bf16)a[kt][1][2]; af[7]=(__bf16)a[kt][1][3];
#pragma unroll
        for (int ct = 0; ct < 8; ++ct)
            acc[ct] = __builtin_amdgcn_mfma_f32_16x16x32_bf16(af, wf[kt][ct], acc[ct], 0, 0, 0);
    }

    // D layout: col = lane&15, row = (lane>>4)*4 + reg  [m89-verified]
    const int orow_base = rowbase + kg * 4;
#pragma unroll
    for (int ct = 0; ct < 8; ++ct) {
        const int col = ct * 16 + r0;
        const float bias = b1[col];
#pragma unroll
        for (int r = 0; r < 4; ++r) {
            const int row = orow_base + r;
            if (row < N_NODES) {
                float v = acc[ct][r] + bias;
                H[row * DIM + col] = (__bf16)(v > 0.f ? v : 0.f);
            }
        }
    }
}

// ---------------- K2a: gather-mean over H rows + concat node feat ----------
// 1 wave/b; 2 rows per iter (8B/lane), 16 independent gathers in flight.
__global__ __launch_bounds__(256)
void pool_concat(const __bf16* __restrict__ H, const float* __restrict__ X,
                 const int* __restrict__ node, const int* __restrict__ nb,
                 __bf16* __restrict__ Cc) {
    const int lane = threadIdx.x & 63;
    const int wave = threadIdx.x >> 6;
    const int b = blockIdx.x * 4 + wave;
    const int hi = lane >> 5;          // 0/1: which row of the pair
    const int lo = lane & 31;          // 8B chunk within row

    __bf16* crow = Cc + (long)b * 256;

    // node feature -> first 128 cols (bf16), 64 lanes x 2 floats
    const int ni = node[b];
    f32x2 nf = *(const f32x2*)(X + (long)ni * DIM + lane * 2);
    union { __bf16 h[2]; uint32_t u; } pk;
    pk.h[0] = (__bf16)nf[0]; pk.h[1] = (__bf16)nf[1];
    *(uint32_t*)(crow + lane * 2) = pk.u;

    const int* nbp = nb + b * K_NB;
    float s0 = 0.f, s1 = 0.f, s2 = 0.f, s3 = 0.f;
#pragma unroll
    for (int i = 0; i < 16; ++i) {
        const int idx = nbp[i * 2 + hi];
        uint2 u = *(const uint2*)(H + (long)idx * DIM + lo * 4);
        s0 += __uint_as_float(u.x << 16);
        s1 += __uint_as_float(u.x & 0xffff0000u);
        s2 += __uint_as_float(u.y << 16);
        s3 += __uint_as_float(u.y & 0xffff0000u);
    }
    // combine the two 16-row halves
    s0 += __shfl_xor(s0, 32);
    s1 += __shfl_xor(s1, 32);
    s2 += __shfl_xor(s2, 32);
    s3 += __shfl_xor(s3, 32);

    if (hi == 0) {
        union { __bf16 h[4]; uint2 u; } pq;
        pq.h[0] = (__bf16)(s0 * (1.0f / K_NB));
        pq.h[1] = (__bf16)(s1 * (1.0f / K_NB));
        pq.h[2] = (__bf16)(s2 * (1.0f / K_NB));
        pq.h[3] = (__bf16)(s3 * (1.0f / K_NB));
        *(uint2*)(crow + 128 + lo * 4) = pq.u;
    }
}

// ---------------- K2b: out = relu(Cc @ Wn), f32 out ----------------
__global__ __launch_bounds__(256, 2)
void gemm_out(const __bf16* __restrict__ Cc, const __bf16* __restrict__ Wnt,
              float* __restrict__ Out) {
    const int lane = threadIdx.x & 63;
    const int wave = threadIdx.x >> 6;
    const int rowbase = blockIdx.x * 64 + wave * 16;
    const int r0 = lane & 15;
    const int kg = lane >> 4;
    const int arow = rowbase + r0;
    const int arow_c = arow < B_BATCH ? arow : B_BATCH - 1;

    // all 8 A fragments up front
    bf16x8 af[8];
#pragma unroll
    for (int kt = 0; kt < 8; ++kt)
        af[kt] = *(const bf16x8*)(Cc + (long)arow_c * 256 + kt * 32 + kg * 8);

    f32x4 acc[8];
#pragma unroll
    for (int t = 0; t < 8; ++t) acc[t] = (f32x4)0.0f;

#pragma unroll
    for (int h = 0; h < 2; ++h) {
        bf16x8 wf[4][8];
#pragma unroll
        for (int kt = 0; kt < 4; ++kt)
#pragma unroll
            for (int ct = 0; ct < 8; ++ct)
                wf[kt][ct] = *(const bf16x8*)(Wnt + (ct * 16 + r0) * 256 + (h * 4 + kt) * 32 + kg * 8);
#pragma unroll
        for (int kt = 0; kt < 4; ++kt)
#pragma unroll
            for (int ct = 0; ct < 8; ++ct)
                acc[ct] = __builtin_amdgcn_mfma_f32_16x16x32_bf16(af[h * 4 + kt], wf[kt][ct], acc[ct], 0, 0, 0);
    }

    const int orow_base = rowbase + kg * 4;
#pragma unroll
    for (int ct = 0; ct < 8; ++ct) {
        const int col = ct * 16 + r0;
#pragma unroll
        for (int r = 0; r < 4; ++r) {
            const int row = orow_base + r;
            if (row < B_BATCH) {
                float v = acc[ct][r];
                Out[(long)row * O_OUT + col] = v > 0.f ? v : 0.f;
            }
        }
    }
}

// ---------------- K3: raw_features passthrough copy ----------------
__global__ __launch_bounds__(256)
void copy_raw(const float4* __restrict__ src, float4* __restrict__ dst, int n4) {
    int i = blockIdx.x * blockDim.x + threadIdx.x;
    const int stride = gridDim.x * blockDim.x;
    for (; i < n4; i += stride) dst[i] = src[i];
}

extern "C" void kernel_launch(void* const* d_in, const int* in_sizes, int n_in,
                              void* d_out, int out_size, void* d_ws, size_t ws_size,
                              hipStream_t stream) {
    const float* features = (const float*)d_in[0];
    const float* raw      = (const float*)d_in[1];
    const float* W1       = (const float*)d_in[2];
    const float* b1       = (const float*)d_in[3];
    const float* Wn       = (const float*)d_in[4];
    const int*   node     = (const int*)d_in[5];
    const int*   nb       = (const int*)d_in[6];
    float* out = (float*)d_out;

    char* ws = (char*)d_ws;
    __bf16* H   = (__bf16*)ws;                          // 25,600,000 B
    __bf16* W1t = (__bf16*)(ws + 25600000);             // 32,768 B
    __bf16* Wnt = (__bf16*)(ws + 25632768);             // 65,536 B
    __bf16* Cc  = (__bf16*)(ws + 25698304);             // 10,240,000 B

    transpose_weights<<<(DIM*DIM + 2*DIM*O_OUT) / 256, 256, 0, stream>>>(W1, Wn, W1t, Wnt);
    gemm_h<<<(N_NODES + 63) / 64, 256, 0, stream>>>(features, W1t, b1, H);
    pool_concat<<<B_BATCH / 4, 256, 0, stream>>>(H, features, node, nb, Cc);
    gemm_out<<<(B_BATCH + 63) / 64, 256, 0, stream>>>(Cc, Wnt, out);
    copy_raw<<<2048, 256, 0, stream>>>((const float4*)raw,
                                       (float4*)(out + (long)B_BATCH * O_OUT),
                                       N_NODES * DIM / 4);
}

// Round 9
// 208.139 us; speedup vs baseline: 1.1228x; 1.1228x over previous
//
#include <hip/hip_runtime.h>
#include <hip/hip_bf16.h>
#include <stdint.h>

typedef __bf16 bf16x8 __attribute__((ext_vector_type(8)));
typedef float  f32x4  __attribute__((ext_vector_type(4)));
typedef float  f32x2  __attribute__((ext_vector_type(2)));

#define N_NODES 100000
#define DIM     128
#define B_BATCH 20000
#define K_NB    32
#define O_OUT   128

// async global->LDS, 16B per lane, dest = wave-uniform base + lane*16
#define GLOAD16(g, l)  __builtin_amdgcn_global_load_lds(                        \
    (const __attribute__((address_space(1))) void*)(g),                         \
    (__attribute__((address_space(3))) void*)(l), 16, 0, 0)

__device__ inline float blo(uint32_t u) { return __uint_as_float(u << 16); }
__device__ inline float bhi(uint32_t u) { return __uint_as_float(u & 0xffff0000u); }

// ---------------- K0: pack weights into MFMA-fragment order (bf16) ----------
// W1f: frag idx ((kt*8+ct)*64+lane)*8+e  <-  W1[k][c], k=kt*32+kg*8+e, c=ct*16+r0
// Wnf: same with K=256 (kt 0..7)         <-  Wn[k][o]
__global__ void prep_weights(const float* __restrict__ W1,
                             const float* __restrict__ Wn,
                             __bf16* __restrict__ W1f,
                             __bf16* __restrict__ Wnf) {
    int tid = blockIdx.x * blockDim.x + threadIdx.x;
    if (tid < 16384) {
        int e = tid & 7, l = (tid >> 3) & 63, ct = (tid >> 9) & 7, kt = tid >> 12;
        int r0 = l & 15, kg = l >> 4;
        W1f[tid] = (__bf16)W1[(kt * 32 + kg * 8 + e) * DIM + ct * 16 + r0];
    }
    int t2 = tid - 16384;
    if (t2 >= 0 && t2 < 32768) {
        int e = t2 & 7, l = (t2 >> 3) & 63, ct = (t2 >> 9) & 7, kt = t2 >> 12;
        int r0 = l & 15, kg = l >> 4;
        Wnf[t2] = (__bf16)Wn[(kt * 32 + kg * 8 + e) * O_OUT + ct * 16 + r0];
    }
}

// ---------------- K1: H = relu(X @ W1 + b1), bf16 out ----------------------
// 64 rows/block. Stage X (32KB, XOR-swizzled source) + W1f (32KB linear) into
// LDS via global_load_lds (16 outstanding 1KB loads/wave -> MLP fix for R7's
// serialized-load stall: VGPR=44 meant ~1 load in flight per CU).
__global__ __launch_bounds__(256, 2)
void gemm_h(const float* __restrict__ X, const __bf16* __restrict__ W1f,
            const float* __restrict__ b1, __bf16* __restrict__ H) {
    __shared__ char lds[65536];
    char* Xs = lds;                 // 64 rows x 512B f32, intra-row XOR swizzle
    char* Wf = lds + 32768;         // fragment-ordered W1 (lane-linear)
    const int tid = threadIdx.x;
    const int lane = tid & 63, wave = tid >> 6;
    const int r0 = lane & 15, kg = lane >> 4;
    const long base = (long)blockIdx.x * 64;

#pragma unroll
    for (int i = 0; i < 8; ++i) {               // X: 2048 chunks of 16B
        int chunk = i * 256 + wave * 64 + lane;
        int lrow = chunk >> 5;
        int coff = (chunk & 31) << 4;
        long grow = base + lrow; if (grow > N_NODES - 1) grow = N_NODES - 1;
        const char* g = (const char*)X + grow * 512 + (coff ^ ((lrow & 7) << 4));
        GLOAD16(g, Xs + chunk * 16);
    }
#pragma unroll
    for (int i = 0; i < 8; ++i) {               // W1f: 2048 chunks, linear
        int chunk = i * 256 + wave * 64 + lane;
        GLOAD16((const char*)W1f + chunk * 16, Wf + chunk * 16);
    }
    __syncthreads();                            // drains vmcnt

    f32x4 acc[8];
#pragma unroll
    for (int t = 0; t < 8; ++t) acc[t] = (f32x4)0.0f;

    const int row = wave * 16 + r0;
    const int swz = (r0 & 7) << 4;              // row&7 == r0&7 (wave*16 % 8 == 0)
#pragma unroll
    for (int kt = 0; kt < 4; ++kt) {
        const int c0 = kt * 128 + kg * 32;      // f32 byte offset of k-chunk
        f32x4 a0 = *(const f32x4*)(Xs + row * 512 + (c0 ^ swz));
        f32x4 a1 = *(const f32x4*)(Xs + row * 512 + ((c0 + 16) ^ swz));
        bf16x8 af;
        af[0]=(__bf16)a0[0]; af[1]=(__bf16)a0[1]; af[2]=(__bf16)a0[2]; af[3]=(__bf16)a0[3];
        af[4]=(__bf16)a1[0]; af[5]=(__bf16)a1[1]; af[6]=(__bf16)a1[2]; af[7]=(__bf16)a1[3];
#pragma unroll
        for (int ct = 0; ct < 8; ++ct) {
            bf16x8 bf = *(const bf16x8*)(Wf + ((kt * 8 + ct) * 64 + lane) * 16);
            acc[ct] = __builtin_amdgcn_mfma_f32_16x16x32_bf16(af, bf, acc[ct], 0, 0, 0);
        }
    }

    // D layout: col = lane&15, row = (lane>>4)*4 + reg  [m89-verified]
    const long orow_base = base + wave * 16 + kg * 4;
#pragma unroll
    for (int ct = 0; ct < 8; ++ct) {
        const int col = ct * 16 + r0;
        const float bias = b1[col];
#pragma unroll
        for (int r = 0; r < 4; ++r) {
            const long orow = orow_base + r;
            if (orow < N_NODES) {
                float v = acc[ct][r] + bias;
                H[orow * DIM + col] = (__bf16)(v > 0.f ? v : 0.f);
            }
        }
    }
}

// ---------------- K2a: gather-mean over H + concat node feat ----------------
// 1 wave/b. Lane (g = lane>>4, c = lane&15): 8 dwordx4 gathers (16B chunks of
// rows g, g+4, ...), shfl-reduce across g. Cc written PRE-SWIZZLED (byte off
// within 512B row ^ ((b&7)<<4)) so gemm_out can stage it linearly.
__global__ __launch_bounds__(256)
void pool_concat(const __bf16* __restrict__ H, const float* __restrict__ X,
                 const int* __restrict__ node, const int* __restrict__ nb,
                 __bf16* __restrict__ Cc) {
    const int lane = threadIdx.x & 63, wave = threadIdx.x >> 6;
    const int b = blockIdx.x * 4 + wave;
    const int g = lane >> 4, c = lane & 15;
    const int swz = (b & 7) << 4;
    char* crow = (char*)Cc + (long)b * 512;

    // node feature -> logical bytes 0..255
    const int ni = node[b];
    f32x2 nf = *(const f32x2*)(X + (long)ni * DIM + lane * 2);
    union { __bf16 h[2]; uint32_t u; } pk;
    pk.h[0] = (__bf16)nf[0]; pk.h[1] = (__bf16)nf[1];
    *(uint32_t*)(crow + ((lane * 4) ^ swz)) = pk.u;

    // pooled mean -> logical bytes 256..511
    const int* nbp = nb + b * K_NB;
    int idx[8];
#pragma unroll
    for (int i = 0; i < 8; ++i) idx[i] = nbp[i * 4 + g];
    float s[8] = {0.f, 0.f, 0.f, 0.f, 0.f, 0.f, 0.f, 0.f};
#pragma unroll
    for (int i = 0; i < 8; ++i) {
        uint4 u = *(const uint4*)(H + (long)idx[i] * DIM + c * 8);
        s[0] += blo(u.x); s[1] += bhi(u.x);
        s[2] += blo(u.y); s[3] += bhi(u.y);
        s[4] += blo(u.z); s[5] += bhi(u.z);
        s[6] += blo(u.w); s[7] += bhi(u.w);
    }
#pragma unroll
    for (int e = 0; e < 8; ++e) {
        s[e] += __shfl_xor(s[e], 16);
        s[e] += __shfl_xor(s[e], 32);
    }
    if (g == 0) {
        union { __bf16 h[8]; uint4 u; } pq;
#pragma unroll
        for (int e = 0; e < 8; ++e) pq.h[e] = (__bf16)(s[e] * (1.0f / K_NB));
        *(uint4*)(crow + ((256 + c * 16) ^ swz)) = pq.u;
    }
}

// ---------------- K2b: out = relu(Cc @ Wn), f32 out -------------------------
// 64 rows/block; A staged linearly (Cc pre-swizzled), W in two 32KB K-halves.
__global__ __launch_bounds__(256, 2)
void gemm_out(const __bf16* __restrict__ Cc, const __bf16* __restrict__ Wnf,
              float* __restrict__ Out) {
    __shared__ char lds[65536];
    char* As = lds;                 // 64 rows x 512B bf16 (swizzled layout)
    char* Wb = lds + 32768;         // current W K-half, fragment order
    const int tid = threadIdx.x;
    const int lane = tid & 63, wave = tid >> 6;
    const int r0 = lane & 15, kg = lane >> 4;
    const long base = (long)blockIdx.x * 64;

#pragma unroll
    for (int i = 0; i < 8; ++i) {               // A: 2048 chunks, linear copy
        int chunk = i * 256 + wave * 64 + lane;
        int lrow = chunk >> 5;
        long grow = base + lrow; if (grow > B_BATCH - 1) grow = B_BATCH - 1;
        const char* g = (const char*)Cc + grow * 512 + ((chunk & 31) << 4);
        GLOAD16(g, As + chunk * 16);
    }
#pragma unroll
    for (int i = 0; i < 8; ++i) {               // W half 0 (kt 0..3)
        int chunk = i * 256 + wave * 64 + lane;
        GLOAD16((const char*)Wnf + chunk * 16, Wb + chunk * 16);
    }
    __syncthreads();

    f32x4 acc[8];
#pragma unroll
    for (int t = 0; t < 8; ++t) acc[t] = (f32x4)0.0f;

    const int row = wave * 16 + r0;
    const int swz = (r0 & 7) << 4;
#pragma unroll
    for (int kt = 0; kt < 4; ++kt) {
        bf16x8 af = *(const bf16x8*)(As + row * 512 + ((kt * 64 + kg * 16) ^ swz));
#pragma unroll
        for (int ct = 0; ct < 8; ++ct) {
            bf16x8 bf = *(const bf16x8*)(Wb + ((kt * 8 + ct) * 64 + lane) * 16);
            acc[ct] = __builtin_amdgcn_mfma_f32_16x16x32_bf16(af, bf, acc[ct], 0, 0, 0);
        }
    }
    __syncthreads();                            // all waves done with W half 0
#pragma unroll
    for (int i = 0; i < 8; ++i) {               // W half 1 (kt 4..7)
        int chunk = i * 256 + wave * 64 + lane;
        GLOAD16((const char*)Wnf + 32768 + chunk * 16, Wb + chunk * 16);
    }
    __syncthreads();
#pragma unroll
    for (int kt = 4; kt < 8; ++kt) {
        bf16x8 af = *(const bf16x8*)(As + row * 512 + ((kt * 64 + kg * 16) ^ swz));
#pragma unroll
        for (int ct = 0; ct < 8; ++ct) {
            bf16x8 bf = *(const bf16x8*)(Wb + (((kt - 4) * 8 + ct) * 64 + lane) * 16);
            acc[ct] = __builtin_amdgcn_mfma_f32_16x16x32_bf16(af, bf, acc[ct], 0, 0, 0);
        }
    }

    const long orow_base = base + wave * 16 + kg * 4;
#pragma unroll
    for (int ct = 0; ct < 8; ++ct) {
        const int col = ct * 16 + r0;
#pragma unroll
        for (int r = 0; r < 4; ++r) {
            const long orow = orow_base + r;
            if (orow < B_BATCH) {
                float v = acc[ct][r];
                Out[orow * O_OUT + col] = v > 0.f ? v : 0.f;
            }
        }
    }
}

// ---------------- K3: raw_features passthrough copy ----------------
__global__ __launch_bounds__(256)
void copy_raw(const float4* __restrict__ src, float4* __restrict__ dst, int n4) {
    int i = blockIdx.x * blockDim.x + threadIdx.x;
    const int stride = gridDim.x * blockDim.x;
    for (; i < n4; i += stride) dst[i] = src[i];
}

extern "C" void kernel_launch(void* const* d_in, const int* in_sizes, int n_in,
                              void* d_out, int out_size, void* d_ws, size_t ws_size,
                              hipStream_t stream) {
    const float* features = (const float*)d_in[0];
    const float* raw      = (const float*)d_in[1];
    const float* W1       = (const float*)d_in[2];
    const float* b1       = (const float*)d_in[3];
    const float* Wn       = (const float*)d_in[4];
    const int*   node     = (const int*)d_in[5];
    const int*   nb       = (const int*)d_in[6];
    float* out = (float*)d_out;

    char* ws = (char*)d_ws;
    __bf16* H   = (__bf16*)ws;                          // 25,600,000 B
    __bf16* W1f = (__bf16*)(ws + 25600000);             // 32,768 B (frag order)
    __bf16* Wnf = (__bf16*)(ws + 25632768);             // 65,536 B (frag order)
    __bf16* Cc  = (__bf16*)(ws + 25698304);             // 10,240,000 B (swizzled rows)

    prep_weights<<<192, 256, 0, stream>>>(W1, Wn, W1f, Wnf);
    gemm_h<<<(N_NODES + 63) / 64, 256, 0, stream>>>(features, W1f, b1, H);
    pool_concat<<<B_BATCH / 4, 256, 0, stream>>>(H, features, node, nb, Cc);
    gemm_out<<<(B_BATCH + 63) / 64, 256, 0, stream>>>(Cc, Wnf, out);
    copy_raw<<<2048, 256, 0, stream>>>((const float4*)raw,
                                       (float4*)(out + (long)B_BATCH * O_OUT),
                                       N_NODES * DIM / 4);
}

// Round 11
// 192.311 us; speedup vs baseline: 1.2152x; 1.0823x over previous
//
#include <hip/hip_runtime.h>
#include <hip/hip_bf16.h>
#include <stdint.h>

typedef __bf16 bf16x8 __attribute__((ext_vector_type(8)));
typedef float  f32x4  __attribute__((ext_vector_type(4)));
typedef float  f32x2  __attribute__((ext_vector_type(2)));

#define N_NODES 100000
#define DIM     128
#define B_BATCH 20000
#define K_NB    32
#define O_OUT   128

// async global->LDS, 16B per lane, dest = wave-uniform base + lane*16
#define GLOAD16(g, l)  __builtin_amdgcn_global_load_lds(                        \
    (const __attribute__((address_space(1))) void*)(g),                         \
    (__attribute__((address_space(3))) void*)(l), 16, 0, 0)

__device__ inline float blo(uint32_t u) { return __uint_as_float(u << 16); }
__device__ inline float bhi(uint32_t u) { return __uint_as_float(u & 0xffff0000u); }

// ---------------- K0: pack weights into MFMA-fragment order (bf16) ----------
// W1f: frag idx ((kt*8+ct)*64+lane)*8+e  <-  W1[k][c], k=kt*32+kg*8+e, c=ct*16+r0
// Wnf: same with K=256 (kt 0..7)         <-  Wn[k][o]
__global__ void prep_weights(const float* __restrict__ W1,
                             const float* __restrict__ Wn,
                             __bf16* __restrict__ W1f,
                             __bf16* __restrict__ Wnf) {
    int tid = blockIdx.x * blockDim.x + threadIdx.x;
    if (tid < 16384) {
        int e = tid & 7, l = (tid >> 3) & 63, ct = (tid >> 9) & 7, kt = tid >> 12;
        int r0 = l & 15, kg = l >> 4;
        W1f[tid] = (__bf16)W1[(kt * 32 + kg * 8 + e) * DIM + ct * 16 + r0];
    }
    int t2 = tid - 16384;
    if (t2 >= 0 && t2 < 32768) {
        int e = t2 & 7, l = (t2 >> 3) & 63, ct = (t2 >> 9) & 7, kt = t2 >> 12;
        int r0 = l & 15, kg = l >> 4;
        Wnf[t2] = (__bf16)Wn[(kt * 32 + kg * 8 + e) * O_OUT + ct * 16 + r0];
    }
}

// stage one 32-row fp32 tile (16KB), XOR-swizzled source, linear LDS dest
__device__ inline void stage_x(const float* X, long tbase, char* dst, int tid) {
#pragma unroll
    for (int i = 0; i < 4; ++i) {
        int c = tid + i * 256;
        int lrow = c >> 5;
        int coff = (c & 31) << 4;
        const char* g = (const char*)X + (tbase + lrow) * 512 + (coff ^ ((lrow & 7) << 4));
        GLOAD16(g, dst + c * 16);
    }
}

// stage one 32-row bf16 tile (16KB) of pre-swizzled Cc, linear copy
__device__ inline void stage_c(const __bf16* Cc, long tbase, char* dst, int tid) {
#pragma unroll
    for (int i = 0; i < 4; ++i) {
        int c = tid + i * 256;
        int lrow = c >> 5;
        const char* g = (const char*)Cc + (tbase + lrow) * 512 + ((c & 31) << 4);
        GLOAD16(g, dst + c * 16);
    }
}

// ---------------- K1: H = relu(X @ W1 + b1), bf16 out ----------------------
// PERSISTENT blocks (512 = 2/CU), W1f resident in LDS, grid-stride tile loop
// with double-buffered async staging: STAGE(next) || compute(cur), counted
// vmcnt(16) so stage loads stay covered without draining the 16 H-stores.
// (R9 showed per-block one-shot staging exposes ~14us latency per 64 rows.)
__global__ __launch_bounds__(256, 2)
void gemm_h(const float* __restrict__ X, const __bf16* __restrict__ W1f,
            const float* __restrict__ b1, __bf16* __restrict__ H) {
    __shared__ char lds[65536];
    char* Wf = lds + 32768;
    const int tid = threadIdx.x;
    const int lane = tid & 63, wave = tid >> 6;
    const int r0 = lane & 15, kg = lane >> 4;
    const int rbase = (wave & 1) * 16;          // wave's 16-row group in 32-row tile
    const int ctbase = (wave >> 1) * 4;         // wave's 4 col-tiles (of 8)
    const int row = rbase + r0;
    const int swz = (r0 & 7) << 4;
    const int NT = N_NODES / 32;                // 3125
    const int NB = gridDim.x;

    float bias[4];
#pragma unroll
    for (int c = 0; c < 4; ++c) bias[c] = b1[(ctbase + c) * 16 + r0];

#pragma unroll
    for (int i = 0; i < 8; ++i) {               // W1f 32KB, loaded once
        int c = tid + i * 256;
        GLOAD16((const char*)W1f + c * 16, Wf + c * 16);
    }
    int t = blockIdx.x;
    char* cur = lds;
    char* nxt = lds + 16384;
    stage_x(X, (long)t * 32, cur, tid);
    asm volatile("s_waitcnt vmcnt(0)" ::: "memory");
    __builtin_amdgcn_s_barrier();

    while (t < NT) {
        const int tn = t + NB;
        if (tn < NT) {
            stage_x(X, (long)tn * 32, nxt, tid);
            asm volatile("" ::: "memory");      // keep stores below stage issues
        }
        f32x4 acc[4];
#pragma unroll
        for (int i = 0; i < 4; ++i) acc[i] = (f32x4)0.0f;
#pragma unroll
        for (int kt = 0; kt < 4; ++kt) {
            const int c0 = kt * 128 + kg * 32;
            f32x4 a0 = *(const f32x4*)(cur + row * 512 + (c0 ^ swz));
            f32x4 a1 = *(const f32x4*)(cur + row * 512 + ((c0 + 16) ^ swz));
            bf16x8 af;
            af[0]=(__bf16)a0[0]; af[1]=(__bf16)a0[1]; af[2]=(__bf16)a0[2]; af[3]=(__bf16)a0[3];
            af[4]=(__bf16)a1[0]; af[5]=(__bf16)a1[1]; af[6]=(__bf16)a1[2]; af[7]=(__bf16)a1[3];
#pragma unroll
            for (int cq = 0; cq < 4; ++cq) {
                bf16x8 bf = *(const bf16x8*)(Wf + ((kt * 8 + ctbase + cq) * 64 + lane) * 16);
                acc[cq] = __builtin_amdgcn_mfma_f32_16x16x32_bf16(af, bf, acc[cq], 0, 0, 0);
            }
        }
        // D layout: col = lane&15, row = (lane>>4)*4 + reg  [m89-verified]
        __bf16* hp = H + ((long)t * 32 + rbase + kg * 4) * DIM + r0;
#pragma unroll
        for (int cq = 0; cq < 4; ++cq) {
#pragma unroll
            for (int r = 0; r < 4; ++r) {
                float v = acc[cq][r] + bias[cq];
                hp[(long)r * DIM + (ctbase + cq) * 16] = (__bf16)(v > 0.f ? v : 0.f);
            }
        }
        if (tn < NT) {
            asm volatile("s_waitcnt vmcnt(16)" ::: "memory");   // 16 newest = H stores
            __builtin_amdgcn_s_barrier();
        }
        char* tmp = cur; cur = nxt; nxt = tmp;
        t = tn;
    }
}

// ---------------- K2a: gather-mean over H + concat node feat ----------------
// 1 wave/b. Lane (g = lane>>4, c = lane&15): 8 dwordx4 gathers, shfl-reduce
// across g. Cc written PRE-SWIZZLED (byte off ^ ((b&7)<<4)) for linear staging.
__global__ __launch_bounds__(256)
void pool_concat(const __bf16* __restrict__ H, const float* __restrict__ X,
                 const int* __restrict__ node, const int* __restrict__ nb,
                 __bf16* __restrict__ Cc) {
    const int lane = threadIdx.x & 63, wave = threadIdx.x >> 6;
    const int b = blockIdx.x * 4 + wave;
    const int g = lane >> 4, c = lane & 15;
    const int swz = (b & 7) << 4;
    char* crow = (char*)Cc + (long)b * 512;

    const int ni = node[b];
    f32x2 nf = *(const f32x2*)(X + (long)ni * DIM + lane * 2);
    union { __bf16 h[2]; uint32_t u; } pk;
    pk.h[0] = (__bf16)nf[0]; pk.h[1] = (__bf16)nf[1];
    *(uint32_t*)(crow + ((lane * 4) ^ swz)) = pk.u;

    const int* nbp = nb + b * K_NB;
    int idx[8];
#pragma unroll
    for (int i = 0; i < 8; ++i) idx[i] = nbp[i * 4 + g];
    float s[8] = {0.f, 0.f, 0.f, 0.f, 0.f, 0.f, 0.f, 0.f};
#pragma unroll
    for (int i = 0; i < 8; ++i) {
        uint4 u = *(const uint4*)(H + (long)idx[i] * DIM + c * 8);
        s[0] += blo(u.x); s[1] += bhi(u.x);
        s[2] += blo(u.y); s[3] += bhi(u.y);
        s[4] += blo(u.z); s[5] += bhi(u.z);
        s[6] += blo(u.w); s[7] += bhi(u.w);
    }
#pragma unroll
    for (int e = 0; e < 8; ++e) {
        s[e] += __shfl_xor(s[e], 16);
        s[e] += __shfl_xor(s[e], 32);
    }
    if (g == 0) {
        union { __bf16 h[8]; uint4 u; } pq;
#pragma unroll
        for (int e = 0; e < 8; ++e) pq.h[e] = (__bf16)(s[e] * (1.0f / K_NB));
        *(uint4*)(crow + ((256 + c * 16) ^ swz)) = pq.u;
    }
}

// ---------------- K2b: out = relu(Cc @ Wn), f32 out -------------------------
// Persistent blocks (256 = 1/CU), Wnf (64KB) resident, dbuf 32-row Cc tiles.
__global__ __launch_bounds__(256, 1)
void gemm_out(const __bf16* __restrict__ Cc, const __bf16* __restrict__ Wnf,
              float* __restrict__ Out) {
    __shared__ char lds[98304];
    char* Wf = lds + 32768;                     // 64KB fragment-ordered Wn
    const int tid = threadIdx.x;
    const int lane = tid & 63, wave = tid >> 6;
    const int r0 = lane & 15, kg = lane >> 4;
    const int rbase = (wave & 1) * 16;
    const int ctbase = (wave >> 1) * 4;
    const int row = rbase + r0;
    const int swz = (r0 & 7) << 4;
    const int NT = B_BATCH / 32;                // 625
    const int NB = gridDim.x;

#pragma unroll
    for (int i = 0; i < 16; ++i) {              // Wnf 64KB, loaded once
        int c = tid + i * 256;
        GLOAD16((const char*)Wnf + c * 16, Wf + c * 16);
    }
    int t = blockIdx.x;
    char* cur = lds;
    char* nxt = lds + 16384;
    stage_c(Cc, (long)t * 32, cur, tid);
    asm volatile("s_waitcnt vmcnt(0)" ::: "memory");
    __builtin_amdgcn_s_barrier();

    while (t < NT) {
        const int tn = t + NB;
        if (tn < NT) {
            stage_c(Cc, (long)tn * 32, nxt, tid);
            asm volatile("" ::: "memory");
        }
        f32x4 acc[4];
#pragma unroll
        for (int i = 0; i < 4; ++i) acc[i] = (f32x4)0.0f;
#pragma unroll
        for (int kt = 0; kt < 8; ++kt) {
            bf16x8 af = *(const bf16x8*)(cur + row * 512 + ((kt * 64 + kg * 16) ^ swz));
#pragma unroll
            for (int cq = 0; cq < 4; ++cq) {
                bf16x8 bf = *(const bf16x8*)(Wf + ((kt * 8 + ctbase + cq) * 64 + lane) * 16);
                acc[cq] = __builtin_amdgcn_mfma_f32_16x16x32_bf16(af, bf, acc[cq], 0, 0, 0);
            }
        }
        float* op = Out + ((long)t * 32 + rbase + kg * 4) * O_OUT + r0;
#pragma unroll
        for (int cq = 0; cq < 4; ++cq) {
#pragma unroll
            for (int r = 0; r < 4; ++r) {
                float v = acc[cq][r];
                op[(long)r * O_OUT + (ctbase + cq) * 16] = v > 0.f ? v : 0.f;
            }
        }
        if (tn < NT) {
            asm volatile("s_waitcnt vmcnt(16)" ::: "memory");
            __builtin_amdgcn_s_barrier();
        }
        char* tmp = cur; cur = nxt; nxt = tmp;
        t = tn;
    }
}

// ---------------- K3: raw_features passthrough copy ----------------
__global__ __launch_bounds__(256)
void copy_raw(const float4* __restrict__ src, float4* __restrict__ dst, int n4) {
    int i = blockIdx.x * blockDim.x + threadIdx.x;
    const int stride = gridDim.x * blockDim.x;
    for (; i < n4; i += stride) dst[i] = src[i];
}

extern "C" void kernel_launch(void* const* d_in, const int* in_sizes, int n_in,
                              void* d_out, int out_size, void* d_ws, size_t ws_size,
                              hipStream_t stream) {
    const float* features = (const float*)d_in[0];
    const float* raw      = (const float*)d_in[1];
    const float* W1       = (const float*)d_in[2];
    const float* b1       = (const float*)d_in[3];
    const float* Wn       = (const float*)d_in[4];
    const int*   node     = (const int*)d_in[5];
    const int*   nb       = (const int*)d_in[6];
    float* out = (float*)d_out;

    char* ws = (char*)d_ws;
    __bf16* H   = (__bf16*)ws;                          // 25,600,000 B
    __bf16* W1f = (__bf16*)(ws + 25600000);             // 32,768 B (frag order)
    __bf16* Wnf = (__bf16*)(ws + 25632768);             // 65,536 B (frag order)
    __bf16* Cc  = (__bf16*)(ws + 25698304);             // 10,240,000 B (swizzled rows)

    prep_weights<<<192, 256, 0, stream>>>(W1, Wn, W1f, Wnf);
    gemm_h<<<512, 256, 0, stream>>>(features, W1f, b1, H);
    pool_concat<<<B_BATCH / 4, 256, 0, stream>>>(H, features, node, nb, Cc);
    gemm_out<<<256, 256, 0, stream>>>(Cc, Wnf, out);
    copy_raw<<<2048, 256, 0, stream>>>((const float4*)raw,
                                       (float4*)(out + (long)B_BATCH * O_OUT),
                                       N_NODES * DIM / 4);
}